// Round 17
// baseline (107.341 us; speedup 1.0000x reference)
//
#include <hip/hip_runtime.h>

typedef int i32x4 __attribute__((ext_vector_type(4)));
typedef float f32x4 __attribute__((ext_vector_type(4)));

#define D_DIM 256
// base-2 scale: sv2 = acc * (1/T) * log2(e) = acc * 2 * 1.442695...
#define C2 2.88539008f
#define LN2 0.69314718f

// ---------------- Kernel 1: L2-normalize -> fp8 e4m3 R[N][256] (linear) -----
__global__ __launch_bounds__(256) void k_normalize(const float* __restrict__ ei,
                                                   const float* __restrict__ ej,
                                                   unsigned char* __restrict__ R,
                                                   unsigned* __restrict__ ticket,
                                                   int B) {
  if (blockIdx.x == 0 && threadIdx.x == 0) *ticket = 0u;  // per-call reset
  const int w = threadIdx.x >> 6, lane = threadIdx.x & 63;
  const int row = blockIdx.x * 16 + w * 4 + (lane >> 4);
  const int kq = lane & 15;
  const float* src = (row < B) ? (ei + (size_t)row * D_DIM)
                               : (ej + (size_t)(row - B) * D_DIM);
  const float4* s4 = (const float4*)src + kq * 4;
  float4 v0 = s4[0], v1 = s4[1], v2 = s4[2], v3 = s4[3];
  float ss = v0.x*v0.x + v0.y*v0.y + v0.z*v0.z + v0.w*v0.w
           + v1.x*v1.x + v1.y*v1.y + v1.z*v1.z + v1.w*v1.w
           + v2.x*v2.x + v2.y*v2.y + v2.z*v2.z + v2.w*v2.w
           + v3.x*v3.x + v3.y*v3.y + v3.z*v3.z + v3.w*v3.w;
#pragma unroll
  for (int d = 1; d < 16; d <<= 1) ss += __shfl_xor(ss, d, 64);  // 16-group
  const float s = 1.0f / fmaxf(sqrtf(ss), 1e-12f);
  int q0 = __builtin_amdgcn_cvt_pk_fp8_f32(v0.x*s, v0.y*s, 0, 0);
  q0     = __builtin_amdgcn_cvt_pk_fp8_f32(v0.z*s, v0.w*s, q0, 1);
  int q1 = __builtin_amdgcn_cvt_pk_fp8_f32(v1.x*s, v1.y*s, 0, 0);
  q1     = __builtin_amdgcn_cvt_pk_fp8_f32(v1.z*s, v1.w*s, q1, 1);
  int q2 = __builtin_amdgcn_cvt_pk_fp8_f32(v2.x*s, v2.y*s, 0, 0);
  q2     = __builtin_amdgcn_cvt_pk_fp8_f32(v2.z*s, v2.w*s, q2, 1);
  int q3 = __builtin_amdgcn_cvt_pk_fp8_f32(v3.x*s, v3.y*s, 0, 0);
  q3     = __builtin_amdgcn_cvt_pk_fp8_f32(v3.z*s, v3.w*s, q3, 1);
  i32x4 o = {q0, q1, q2, q3};
  ((i32x4*)R)[(size_t)row * 16 + kq] = o;  // linear: row*256B + kq*16B
}

// ---------------- Kernel 2: symmetric fused sim GEMM + exp partials ---------
// R13's compute/epilogue with the one evidence-backed lever applied:
// OCCUPANCY. BK=32 fp8 dbuf -> LDS 16KB/block; __launch_bounds__(256,6)
// -> 6 blocks/CU (vs R13's measured ~2.3 effective). 16 rounds showed
// blocks/CU is the only variable that moves the DMA-latency-dominated
// per-tile cost; barrier count / prefetch depth / dtype all proved
// non-causal. Linear LDS (no swizzle): at BK=32, b64 frag reads hit all
// 16 even banks at exactly 4 lanes/bank -- the 8B-aligned floor.
__global__ __launch_bounds__(256, 6) void k_simgemm(const unsigned char* __restrict__ R,
                                                    float* __restrict__ rowPartial,
                                                    float* __restrict__ simTgt,
                                                    int N) {
  __shared__ char lds[2][8 * 1024];  // per buf: A panel 4KB + B panel 4KB
  const int tid = threadIdx.x;
  const int w = tid >> 6, lane = tid & 63;
  const int wr = w >> 1, wc = w & 1;
  const int c15 = lane & 15, g = lane >> 4;
  const int half = N >> 1;

  // decode linear block id -> upper-triangular (bi, bj), bi <= bj
  const int T = N / 128;  // 64
  const int t = blockIdx.x;
  int bi = (int)(((float)(2 * T + 1) -
                  sqrtf((float)((2 * T + 1) * (2 * T + 1) - 8 * t))) * 0.5f);
  while (bi > 0 && t < bi * (2 * T - bi + 1) / 2) --bi;
  while (t >= (bi + 1) * (2 * T - bi) / 2) ++bi;
  const int bj = bi + (t - bi * (2 * T - bi + 1) / 2);
  const int brow = bi * 128, bcol = bj * 128;
  const bool offdiag = (bi != bj);

  f32x4 acc[4][4];
#pragma unroll
  for (int m = 0; m < 4; ++m)
#pragma unroll
    for (int n = 0; n < 4; ++n) acc[m][n] = (f32x4){0.f, 0.f, 0.f, 0.f};

  // stage one BK=32 fp8 K-slice (A 128 rows | B 128 cols), linear, 2/thread
  auto stage = [&](int buf, int kt) {
    char* dst = lds[buf];
#pragma unroll
    for (int i = 0; i < 2; ++i) {
      const int cid = i * 256 + tid;        // 16B-chunk id, 0..511
      const int panel = cid >> 8;           // 0 = A rows, 1 = B cols
      const int pc = cid & 255;
      const int r = pc >> 1, c = pc & 1;
      const unsigned char* gp =
          R + (size_t)((panel ? bcol : brow) + r) * 256 + kt * 32 + c * 16;
      __builtin_amdgcn_global_load_lds(
          (const __attribute__((address_space(1))) void*)gp,
          (__attribute__((address_space(3))) void*)(dst + (size_t)cid * 16), 16, 0, 0);
    }
  };

  auto compute = [&](int buf) {
    const char* ldsA = lds[buf];
    const char* ldsB = lds[buf] + 4 * 1024;
    long a[4], b[4];
#pragma unroll
    for (int m = 0; m < 4; ++m)
      a[m] = *(const long*)(ldsA + (wr * 64 + m * 16 + c15) * 32 + g * 8);
#pragma unroll
    for (int n = 0; n < 4; ++n)
      b[n] = *(const long*)(ldsB + (wc * 64 + n * 16 + c15) * 32 + g * 8);
#pragma unroll
    for (int m = 0; m < 4; ++m)
#pragma unroll
      for (int n = 0; n < 4; ++n)
        acc[m][n] = __builtin_amdgcn_mfma_f32_16x16x32_fp8_fp8(a[m], b[n], acc[m][n], 0, 0, 0);
  };

  stage(0, 0);  // prologue: 2 loads/thread in flight
#pragma unroll
  for (int kt = 0; kt < 8; ++kt) {  // K = 256 = 8 * 32
    const int cur = kt & 1;
    if (kt < 7) {
      stage(cur ^ 1, kt + 1);                       // +2 in flight
      asm volatile("s_waitcnt vmcnt(2)" ::: "memory");  // cur's 2 landed
    } else {
      asm volatile("s_waitcnt vmcnt(0)" ::: "memory");
    }
    __builtin_amdgcn_s_barrier();   // all waves' cur-buf writes visible
    compute(cur);
    __builtin_amdgcn_s_barrier();   // all reads of cur done before overwrite
  }

  // epilogue (base-2): mask diag, capture targets, exp2, row-dir sums
  // (over tile cols) + col-dir sums (over rows, symmetry)
  float cs4[4] = {0.f, 0.f, 0.f, 0.f};
#pragma unroll
  for (int m = 0; m < 4; ++m) {
#pragma unroll
    for (int j = 0; j < 4; ++j) {
      const int gr = brow + wr * 64 + m * 16 + g * 4 + j;
      const int tgt = (gr < half) ? gr + half : gr - half;
      float rs = 0.f;
#pragma unroll
      for (int n = 0; n < 4; ++n) {
        const int gc = bcol + wc * 64 + n * 16 + c15;
        const float sv2 = acc[m][n][j] * C2;
        const float ev = (gr == gc) ? 0.f : __builtin_amdgcn_exp2f(sv2);
        if (gc == tgt) {                  // involution: also gr == tgt(gc)
          simTgt[gr] = sv2;
          if (offdiag) simTgt[gc] = sv2;  // sim symmetric
        }
        rs += ev;
        cs4[n] += ev;
      }
#pragma unroll
      for (int d = 1; d < 16; d <<= 1) rs += __shfl_xor(rs, d, 64);
      if (c15 == 0)
        rowPartial[(size_t)(bj * 2 + wc) * N + gr] = rs;
    }
  }
  if (offdiag) {  // column block receives row-sums of the transposed tile
#pragma unroll
    for (int n = 0; n < 4; ++n) {
      float c = cs4[n];
      c += __shfl_xor(c, 16, 64);
      c += __shfl_xor(c, 32, 64);
      if (g == 0)
        rowPartial[(size_t)(bi * 2 + wr) * N + (bcol + wc * 64 + n * 16 + c15)] = c;
    }
  }
}

// ---------------- Kernel 3: row logsumexp-target + deterministic final mean --
__global__ __launch_bounds__(256) void k_rowreduce(const float* __restrict__ rowPartial,
                                                   const float* __restrict__ simTgt,
                                                   float* __restrict__ blockOut,
                                                   unsigned* __restrict__ ticket,
                                                   float* __restrict__ out, int N) {
  const int lane = threadIdx.x & 63;   // row within this block's 64
  const int q = threadIdx.x >> 6;      // partial-chunk 0..3
  const int row = blockIdx.x * 64 + lane;
  float part = 0.f;
#pragma unroll 8
  for (int c = q * 32; c < q * 32 + 32; ++c)
    part += rowPartial[(size_t)c * N + row];
  __shared__ float red[4][64];
  __shared__ int isLast;
  red[q][lane] = part;
  __syncthreads();
  if (threadIdx.x < 64) {
    const float denom = red[0][lane] + red[1][lane] + red[2][lane] + red[3][lane];
    // v_log_f32 = log2; loss = (log2(denom) - sv2) * ln2
    float lossr = (__builtin_amdgcn_logf(denom) - simTgt[row]) * LN2;
#pragma unroll
    for (int d = 32; d; d >>= 1) lossr += __shfl_xor(lossr, d, 64);
    if (threadIdx.x == 0) {
      // device-scope RMW write: coherent across XCDs, deterministic value
      atomicExch(&blockOut[blockIdx.x], lossr);
      isLast = (atomicAdd(ticket, 1u) == gridDim.x - 1);
    }
  }
  __syncthreads();
  if (isLast && threadIdx.x < 64) {
    // coherent read of all 128 block sums via atomic RMW (+0.0f), fixed order
    float v = atomicAdd(&blockOut[threadIdx.x], 0.0f) +
              atomicAdd(&blockOut[64 + threadIdx.x], 0.0f);
#pragma unroll
    for (int d = 32; d; d >>= 1) v += __shfl_xor(v, d, 64);
    if (threadIdx.x == 0) out[0] = v / (float)N;
  }
}

extern "C" void kernel_launch(void* const* d_in, const int* in_sizes, int n_in,
                              void* d_out, int out_size, void* d_ws, size_t ws_size,
                              hipStream_t stream) {
  const float* ei = (const float*)d_in[0];
  const float* ej = (const float*)d_in[1];
  const int B = in_sizes[0] / D_DIM;  // 4096
  const int N = 2 * B;                // 8192

  char* ws = (char*)d_ws;
  unsigned char* R = (unsigned char*)ws;                                  // N*256 = 2MB (fp8)
  float* rowPartial = (float*)(ws + (size_t)N * D_DIM);                   // 128*N*4 = 4MB
  float* simTgt     = (float*)(ws + (size_t)N * D_DIM + (size_t)128 * N * 4);  // N*4
  float* blockOut   = (float*)((char*)simTgt + (size_t)N * 4);            // 128*4
  unsigned* ticket  = (unsigned*)((char*)blockOut + 128 * 4);             // 4B

  k_normalize<<<N / 16, 256, 0, stream>>>(ei, ej, R, ticket, B);
  const int T = N / 128;
  k_simgemm<<<T * (T + 1) / 2, 256, 0, stream>>>(R, rowPartial, simTgt, N);
  k_rowreduce<<<N / 64, 256, 0, stream>>>(rowPartial, simTgt, blockOut, ticket,
                                          (float*)d_out, N);
}

// Round 18
// 56.822 us; speedup vs baseline: 1.8891x; 1.8891x over previous
//
#include <hip/hip_runtime.h>

typedef int i32x4 __attribute__((ext_vector_type(4)));
typedef float f32x4 __attribute__((ext_vector_type(4)));

#define D_DIM 256
// base-2 scale: sv2 = acc * (1/T) * log2(e) = acc * 2 * 1.442695...
#define C2 2.88539008f
#define LN2 0.69314718f

// Fragment-native fp8 L-layout: byte(row, k) at
//   ((row>>4)*8 + (k>>5))*512 + (row&15)*32 + (k&31)
// One MFMA fragment (16 rows x 32 k) = 512 CONTIGUOUS bytes; a wave's
// 64 lanes x 8B tile it exactly (lane offset (lane&15)*32 + (lane>>4)*8).

// ---------------- Kernel 1: L2-normalize -> fp8 e4m3 L-layout R -------------
__global__ __launch_bounds__(256) void k_normalize(const float* __restrict__ ei,
                                                   const float* __restrict__ ej,
                                                   unsigned char* __restrict__ R,
                                                   unsigned* __restrict__ ticket,
                                                   int B) {
  if (blockIdx.x == 0 && threadIdx.x == 0) *ticket = 0u;  // per-call reset
  const int w = threadIdx.x >> 6, lane = threadIdx.x & 63;
  const int row = blockIdx.x * 16 + w * 4 + (lane >> 4);
  const int kq = lane & 15;  // owns k in [kq*16, kq*16+16)
  const float* src = (row < B) ? (ei + (size_t)row * D_DIM)
                               : (ej + (size_t)(row - B) * D_DIM);
  const float4* s4 = (const float4*)src + kq * 4;
  float4 v0 = s4[0], v1 = s4[1], v2 = s4[2], v3 = s4[3];
  float ss = v0.x*v0.x + v0.y*v0.y + v0.z*v0.z + v0.w*v0.w
           + v1.x*v1.x + v1.y*v1.y + v1.z*v1.z + v1.w*v1.w
           + v2.x*v2.x + v2.y*v2.y + v2.z*v2.z + v2.w*v2.w
           + v3.x*v3.x + v3.y*v3.y + v3.z*v3.z + v3.w*v3.w;
#pragma unroll
  for (int d = 1; d < 16; d <<= 1) ss += __shfl_xor(ss, d, 64);  // 16-group
  const float s = 1.0f / fmaxf(sqrtf(ss), 1e-12f);
  int q0 = __builtin_amdgcn_cvt_pk_fp8_f32(v0.x*s, v0.y*s, 0, 0);
  q0     = __builtin_amdgcn_cvt_pk_fp8_f32(v0.z*s, v0.w*s, q0, 1);
  int q1 = __builtin_amdgcn_cvt_pk_fp8_f32(v1.x*s, v1.y*s, 0, 0);
  q1     = __builtin_amdgcn_cvt_pk_fp8_f32(v1.z*s, v1.w*s, q1, 1);
  int q2 = __builtin_amdgcn_cvt_pk_fp8_f32(v2.x*s, v2.y*s, 0, 0);
  q2     = __builtin_amdgcn_cvt_pk_fp8_f32(v2.z*s, v2.w*s, q2, 1);
  int q3 = __builtin_amdgcn_cvt_pk_fp8_f32(v3.x*s, v3.y*s, 0, 0);
  q3     = __builtin_amdgcn_cvt_pk_fp8_f32(v3.z*s, v3.w*s, q3, 1);
  i32x4 o = {q0, q1, q2, q3};
  // L-layout: kt = kq>>1, 16B half = kq&1
  const size_t idx = (((size_t)(row >> 4) * 8 + (kq >> 1)) * 16 + (row & 15)) * 32
                   + (size_t)(kq & 1) * 16;
  *(i32x4*)(R + idx) = o;
}

// ---------------- Kernel 2: A-in-LDS / B-direct symmetric sim GEMM ----------
// Insight from R5..R17 byte accounting: every global_load_lds variant runs
// at only ~5-8 TB/s effective -- the DMA path is the bottleneck. So: stage
// ONLY the A panel (full-K, 32KB contiguous in L-layout) once per block --
// one vmcnt(0) + one barrier -- and load B fragments DIRECT global->VGPR
// (512B contiguous per wave-load in L-layout; the loads R16 validated).
// DMA bytes halve (133->66MB); K-loop has ZERO barriers; B comes through
// the normal L1/L2 path. 4 waves/SIMD (acc 64 AGPR + ~50 VGPR) hide B's
// L2 latency.
__global__ __launch_bounds__(256) void k_simgemm(const unsigned char* __restrict__ R,
                                                 float* __restrict__ rowPartial,
                                                 float* __restrict__ simTgt,
                                                 int N) {
  __shared__ char ldsA[32 * 1024];  // A panel, full K, L-layout (read-only)
  const int tid = threadIdx.x;
  const int w = tid >> 6, lane = tid & 63;
  const int wr = w >> 1, wc = w & 1;
  const int c15 = lane & 15, g = lane >> 4;
  const int half = N >> 1;

  // decode linear block id -> upper-triangular (bi, bj), bi <= bj
  const int T = N / 128;  // 64
  const int t = blockIdx.x;
  int bi = (int)(((float)(2 * T + 1) -
                  sqrtf((float)((2 * T + 1) * (2 * T + 1) - 8 * t))) * 0.5f);
  while (bi > 0 && t < bi * (2 * T - bi + 1) / 2) --bi;
  while (t >= (bi + 1) * (2 * T - bi) / 2) ++bi;
  const int bj = bi + (t - bi * (2 * T - bi + 1) / 2);
  const int brow = bi * 128, bcol = bj * 128;
  const bool offdiag = (bi != bj);

  // ---- stage A panel: 32KB contiguous (L-layout), linear src -> linear dst
  const unsigned char* Asrc = R + (size_t)(brow >> 4) * 4096;
#pragma unroll
  for (int i = 0; i < 8; ++i) {
    const int cid = i * 256 + tid;  // 16B chunk 0..2047
    __builtin_amdgcn_global_load_lds(
        (const __attribute__((address_space(1))) void*)(Asrc + (size_t)cid * 16),
        (__attribute__((address_space(3))) void*)(ldsA + (size_t)cid * 16), 16, 0, 0);
  }
  asm volatile("s_waitcnt vmcnt(0)" ::: "memory");
  __builtin_amdgcn_s_barrier();  // the only barrier; LDS read-only after

  f32x4 acc[4][4];
#pragma unroll
  for (int m = 0; m < 4; ++m)
#pragma unroll
    for (int n = 0; n < 4; ++n) acc[m][n] = (f32x4){0.f, 0.f, 0.f, 0.f};

  const size_t laneOff = (size_t)c15 * 32 + (size_t)g * 8;
  const char* Ab = ldsA + (size_t)(wr * 4) * 4096 + laneOff;
  const char* Bb = (const char*)R + ((size_t)(bcol >> 4) + wc * 4) * 4096 + laneOff;

#pragma unroll
  for (int kt = 0; kt < 8; ++kt) {  // K = 256 = 8 * 32, no barriers
    long a[4], b[4];
#pragma unroll
    for (int n = 0; n < 4; ++n)
      b[n] = *(const long*)(Bb + (size_t)n * 4096 + (size_t)kt * 512);
#pragma unroll
    for (int m = 0; m < 4; ++m)
      a[m] = *(const long*)(Ab + (size_t)m * 4096 + (size_t)kt * 512);
#pragma unroll
    for (int m = 0; m < 4; ++m)
#pragma unroll
      for (int n = 0; n < 4; ++n)
        acc[m][n] = __builtin_amdgcn_mfma_f32_16x16x32_fp8_fp8(a[m], b[n], acc[m][n], 0, 0, 0);
  }

  // epilogue (base-2): mask diag, capture targets, exp2, row-dir sums
  // (over tile cols) + col-dir sums (over rows, symmetry). R13 scheme.
  float cs4[4] = {0.f, 0.f, 0.f, 0.f};
#pragma unroll
  for (int m = 0; m < 4; ++m) {
#pragma unroll
    for (int j = 0; j < 4; ++j) {
      const int gr = brow + wr * 64 + m * 16 + g * 4 + j;
      const int tgt = (gr < half) ? gr + half : gr - half;
      float rs = 0.f;
#pragma unroll
      for (int n = 0; n < 4; ++n) {
        const int gc = bcol + wc * 64 + n * 16 + c15;
        const float sv2 = acc[m][n][j] * C2;
        const float ev = (gr == gc) ? 0.f : __builtin_amdgcn_exp2f(sv2);
        if (gc == tgt) {                  // involution: also gr == tgt(gc)
          simTgt[gr] = sv2;
          if (offdiag) simTgt[gc] = sv2;  // sim symmetric
        }
        rs += ev;
        cs4[n] += ev;
      }
#pragma unroll
      for (int d = 1; d < 16; d <<= 1) rs += __shfl_xor(rs, d, 64);
      if (c15 == 0)
        rowPartial[(size_t)(bj * 2 + wc) * N + gr] = rs;
    }
  }
  if (offdiag) {  // column block receives row-sums of the transposed tile
#pragma unroll
    for (int n = 0; n < 4; ++n) {
      float c = cs4[n];
      c += __shfl_xor(c, 16, 64);
      c += __shfl_xor(c, 32, 64);
      if (g == 0)
        rowPartial[(size_t)(bi * 2 + wr) * N + (bcol + wc * 64 + n * 16 + c15)] = c;
    }
  }
}

// ---------------- Kernel 3: row logsumexp-target + deterministic final mean --
__global__ __launch_bounds__(256) void k_rowreduce(const float* __restrict__ rowPartial,
                                                   const float* __restrict__ simTgt,
                                                   float* __restrict__ blockOut,
                                                   unsigned* __restrict__ ticket,
                                                   float* __restrict__ out, int N) {
  const int lane = threadIdx.x & 63;   // row within this block's 64
  const int q = threadIdx.x >> 6;      // partial-chunk 0..3
  const int row = blockIdx.x * 64 + lane;
  float part = 0.f;
#pragma unroll 8
  for (int c = q * 32; c < q * 32 + 32; ++c)
    part += rowPartial[(size_t)c * N + row];
  __shared__ float red[4][64];
  __shared__ int isLast;
  red[q][lane] = part;
  __syncthreads();
  if (threadIdx.x < 64) {
    const float denom = red[0][lane] + red[1][lane] + red[2][lane] + red[3][lane];
    // v_log_f32 = log2; loss = (log2(denom) - sv2) * ln2
    float lossr = (__builtin_amdgcn_logf(denom) - simTgt[row]) * LN2;
#pragma unroll
    for (int d = 32; d; d >>= 1) lossr += __shfl_xor(lossr, d, 64);
    if (threadIdx.x == 0) {
      // device-scope RMW write: coherent across XCDs, deterministic value
      atomicExch(&blockOut[blockIdx.x], lossr);
      isLast = (atomicAdd(ticket, 1u) == gridDim.x - 1);
    }
  }
  __syncthreads();
  if (isLast && threadIdx.x < 64) {
    // coherent read of all 128 block sums via atomic RMW (+0.0f), fixed order
    float v = atomicAdd(&blockOut[threadIdx.x], 0.0f) +
              atomicAdd(&blockOut[64 + threadIdx.x], 0.0f);
#pragma unroll
    for (int d = 32; d; d >>= 1) v += __shfl_xor(v, d, 64);
    if (threadIdx.x == 0) out[0] = v / (float)N;
  }
}

extern "C" void kernel_launch(void* const* d_in, const int* in_sizes, int n_in,
                              void* d_out, int out_size, void* d_ws, size_t ws_size,
                              hipStream_t stream) {
  const float* ei = (const float*)d_in[0];
  const float* ej = (const float*)d_in[1];
  const int B = in_sizes[0] / D_DIM;  // 4096
  const int N = 2 * B;                // 8192

  char* ws = (char*)d_ws;
  unsigned char* R = (unsigned char*)ws;                                  // N*256 = 2MB (fp8, L-layout)
  float* rowPartial = (float*)(ws + (size_t)N * D_DIM);                   // 128*N*4 = 4MB
  float* simTgt     = (float*)(ws + (size_t)N * D_DIM + (size_t)128 * N * 4);  // N*4
  float* blockOut   = (float*)((char*)simTgt + (size_t)N * 4);            // 128*4
  unsigned* ticket  = (unsigned*)((char*)blockOut + 128 * 4);             // 4B

  k_normalize<<<N / 16, 256, 0, stream>>>(ei, ej, R, ticket, B);
  const int T = N / 128;
  k_simgemm<<<T * (T + 1) / 2, 256, 0, stream>>>(R, rowPartial, simTgt, N);
  k_rowreduce<<<N / 64, 256, 0, stream>>>(rowPartial, simTgt, blockOut, ticket,
                                          (float*)d_out, N);
}

// Round 19
// 43.951 us; speedup vs baseline: 2.4423x; 1.2928x over previous
//
#include <hip/hip_runtime.h>

typedef int i32x4 __attribute__((ext_vector_type(4)));
typedef float f32x4 __attribute__((ext_vector_type(4)));

#define D_DIM 256
// base-2 scale: sv2 = acc * (1/T) * log2(e) = acc * 2 * 1.442695...
#define C2 2.88539008f
#define LN2 0.69314718f

// ---------------- Kernel 1: L2-normalize -> fp8 e4m3 R[N][256] (linear) -----
__global__ __launch_bounds__(256) void k_normalize(const float* __restrict__ ei,
                                                   const float* __restrict__ ej,
                                                   unsigned char* __restrict__ R,
                                                   unsigned* __restrict__ ticket,
                                                   int B) {
  if (blockIdx.x == 0 && threadIdx.x == 0) *ticket = 0u;  // per-call reset
  const int w = threadIdx.x >> 6, lane = threadIdx.x & 63;
  const int row = blockIdx.x * 16 + w * 4 + (lane >> 4);
  const int kq = lane & 15;
  const float* src = (row < B) ? (ei + (size_t)row * D_DIM)
                               : (ej + (size_t)(row - B) * D_DIM);
  const float4* s4 = (const float4*)src + kq * 4;
  float4 v0 = s4[0], v1 = s4[1], v2 = s4[2], v3 = s4[3];
  float ss = v0.x*v0.x + v0.y*v0.y + v0.z*v0.z + v0.w*v0.w
           + v1.x*v1.x + v1.y*v1.y + v1.z*v1.z + v1.w*v1.w
           + v2.x*v2.x + v2.y*v2.y + v2.z*v2.z + v2.w*v2.w
           + v3.x*v3.x + v3.y*v3.y + v3.z*v3.z + v3.w*v3.w;
#pragma unroll
  for (int d = 1; d < 16; d <<= 1) ss += __shfl_xor(ss, d, 64);  // 16-group
  const float s = 1.0f / fmaxf(sqrtf(ss), 1e-12f);
  int q0 = __builtin_amdgcn_cvt_pk_fp8_f32(v0.x*s, v0.y*s, 0, 0);
  q0     = __builtin_amdgcn_cvt_pk_fp8_f32(v0.z*s, v0.w*s, q0, 1);
  int q1 = __builtin_amdgcn_cvt_pk_fp8_f32(v1.x*s, v1.y*s, 0, 0);
  q1     = __builtin_amdgcn_cvt_pk_fp8_f32(v1.z*s, v1.w*s, q1, 1);
  int q2 = __builtin_amdgcn_cvt_pk_fp8_f32(v2.x*s, v2.y*s, 0, 0);
  q2     = __builtin_amdgcn_cvt_pk_fp8_f32(v2.z*s, v2.w*s, q2, 1);
  int q3 = __builtin_amdgcn_cvt_pk_fp8_f32(v3.x*s, v3.y*s, 0, 0);
  q3     = __builtin_amdgcn_cvt_pk_fp8_f32(v3.z*s, v3.w*s, q3, 1);
  i32x4 o = {q0, q1, q2, q3};
  ((i32x4*)R)[(size_t)row * 16 + kq] = o;  // linear: row*256B + kq*16B
}

// ---------------- Kernel 2: symmetric fused sim GEMM + exp partials ---------
// R13 (measured best, 44.3us total): fp8 BK=64 dbuf, counted vmcnt,
// 2 barriers/step, (256,4) -> 4 blocks/CU, inter-block TLP hides DMA
// latency. Swizzled LDS chunks; b64 frag reads at the inherent 512B/instr
// throughput floor. mfma_f32_16x16x32_fp8_fp8, absmax 0 end-to-end.
__global__ __launch_bounds__(256, 4) void k_simgemm(const unsigned char* __restrict__ R,
                                                    float* __restrict__ rowPartial,
                                                    float* __restrict__ simTgt,
                                                    int N) {
  __shared__ char lds[2][16 * 1024];  // per buf: A panel 8KB + B panel 8KB
  const int tid = threadIdx.x;
  const int w = tid >> 6, lane = tid & 63;
  const int wr = w >> 1, wc = w & 1;
  const int half = N >> 1;

  // decode linear block id -> upper-triangular (bi, bj), bi <= bj
  const int T = N / 128;  // 64
  const int t = blockIdx.x;
  int bi = (int)(((float)(2 * T + 1) -
                  sqrtf((float)((2 * T + 1) * (2 * T + 1) - 8 * t))) * 0.5f);
  while (bi > 0 && t < bi * (2 * T - bi + 1) / 2) --bi;
  while (t >= (bi + 1) * (2 * T - bi) / 2) ++bi;
  const int bj = bi + (t - bi * (2 * T - bi + 1) / 2);
  const int brow = bi * 128, bcol = bj * 128;
  const bool offdiag = (bi != bj);

  f32x4 acc[4][4];
#pragma unroll
  for (int m = 0; m < 4; ++m)
#pragma unroll
    for (int n = 0; n < 4; ++n) acc[m][n] = (f32x4){0.f, 0.f, 0.f, 0.f};

  // stage one BK=64 fp8 K-slice (A rows | B cols) into lds[buf].
  // Row = 64B = 4 chunks of 16B; swizzle slot cs holds chunk cs^((r>>1)&3).
  auto stage = [&](int buf, int kt) {
    char* dst = lds[buf];
#pragma unroll
    for (int i = 0; i < 4; ++i) {
      const int cid = i * 256 + tid;        // 16B-chunk id, 0..1023
      const int panel = cid >> 9;           // 0 = A rows, 1 = B cols
      const int pc = cid & 511;
      const int r = pc >> 2, cs = pc & 3;
      const int c = cs ^ ((r >> 1) & 3);    // inverse swizzle on source
      const unsigned char* g =
          R + (size_t)((panel ? bcol : brow) + r) * 256 + kt * 64 + c * 16;
      __builtin_amdgcn_global_load_lds(
          (const __attribute__((address_space(1))) void*)g,
          (__attribute__((address_space(3))) void*)(dst + (size_t)cid * 16), 16, 0, 0);
    }
  };

  auto compute = [&](int buf) {
    const char* ldsA = lds[buf];
    const char* ldsB = lds[buf] + 8 * 1024;
    const int g = lane >> 4, c15 = lane & 15;
    long a[4][2], b[4][2];
#pragma unroll
    for (int m = 0; m < 4; ++m) {
      const int row = wr * 64 + m * 16 + c15;
      const int sw = (row >> 1) & 3;
#pragma unroll
      for (int ks = 0; ks < 2; ++ks) {
        const int chunk = (ks * 2 + (g >> 1)) ^ sw;
        a[m][ks] = *(const long*)(ldsA + row * 64 + chunk * 16 + (g & 1) * 8);
      }
    }
#pragma unroll
    for (int n = 0; n < 4; ++n) {
      const int col = wc * 64 + n * 16 + c15;
      const int sw = (col >> 1) & 3;
#pragma unroll
      for (int ks = 0; ks < 2; ++ks) {
        const int chunk = (ks * 2 + (g >> 1)) ^ sw;
        b[n][ks] = *(const long*)(ldsB + col * 64 + chunk * 16 + (g & 1) * 8);
      }
    }
#pragma unroll
    for (int ks = 0; ks < 2; ++ks)
#pragma unroll
      for (int m = 0; m < 4; ++m)
#pragma unroll
        for (int n = 0; n < 4; ++n)
          acc[m][n] = __builtin_amdgcn_mfma_f32_16x16x32_fp8_fp8(
              a[m][ks], b[n][ks], acc[m][n], 0, 0, 0);
  };

  stage(0, 0);  // prologue: 4 loads/thread in flight
#pragma unroll
  for (int kt = 0; kt < 4; ++kt) {  // K = 256 = 4 * 64
    const int cur = kt & 1;
    if (kt < 3) {
      stage(cur ^ 1, kt + 1);                       // +4 in flight
      asm volatile("s_waitcnt vmcnt(4)" ::: "memory");  // cur's 4 landed
    } else {
      asm volatile("s_waitcnt vmcnt(0)" ::: "memory");
    }
    __builtin_amdgcn_s_barrier();   // all waves' cur-buf writes visible
    compute(cur);
    __builtin_amdgcn_s_barrier();   // all reads of cur done before overwrite
  }

  // epilogue (base-2): mask diag, capture targets, exp2, row-direction
  // sums (over tile cols) + column-direction sums (over rows, symmetry)
  float cs4[4] = {0.f, 0.f, 0.f, 0.f};
#pragma unroll
  for (int m = 0; m < 4; ++m) {
#pragma unroll
    for (int j = 0; j < 4; ++j) {
      const int gr = brow + wr * 64 + m * 16 + (lane >> 4) * 4 + j;
      const int tgt = (gr < half) ? gr + half : gr - half;
      float rs = 0.f;
#pragma unroll
      for (int n = 0; n < 4; ++n) {
        const int gc = bcol + wc * 64 + n * 16 + (lane & 15);
        const float sv2 = acc[m][n][j] * C2;
        const float ev = (gr == gc) ? 0.f : __builtin_amdgcn_exp2f(sv2);
        if (gc == tgt) {                  // involution: also gr == tgt(gc)
          simTgt[gr] = sv2;
          if (offdiag) simTgt[gc] = sv2;  // sim symmetric
        }
        rs += ev;
        cs4[n] += ev;
      }
#pragma unroll
      for (int d = 1; d < 16; d <<= 1) rs += __shfl_xor(rs, d, 64);
      if ((lane & 15) == 0)
        rowPartial[(size_t)(bj * 2 + wc) * N + gr] = rs;
    }
  }
  if (offdiag) {  // column block receives row-sums of the transposed tile
#pragma unroll
    for (int n = 0; n < 4; ++n) {
      float c = cs4[n];
      c += __shfl_xor(c, 16, 64);
      c += __shfl_xor(c, 32, 64);
      if ((lane >> 4) == 0)
        rowPartial[(size_t)(bi * 2 + wr) * N + (bcol + wc * 64 + n * 16 + (lane & 15))] = c;
    }
  }
}

// ---------------- Kernel 3: row logsumexp-target + deterministic final mean --
__global__ __launch_bounds__(256) void k_rowreduce(const float* __restrict__ rowPartial,
                                                   const float* __restrict__ simTgt,
                                                   float* __restrict__ blockOut,
                                                   unsigned* __restrict__ ticket,
                                                   float* __restrict__ out, int N) {
  const int lane = threadIdx.x & 63;   // row within this block's 64
  const int q = threadIdx.x >> 6;      // partial-chunk 0..3
  const int row = blockIdx.x * 64 + lane;
  float part = 0.f;
#pragma unroll 8
  for (int c = q * 32; c < q * 32 + 32; ++c)
    part += rowPartial[(size_t)c * N + row];
  __shared__ float red[4][64];
  __shared__ int isLast;
  red[q][lane] = part;
  __syncthreads();
  if (threadIdx.x < 64) {
    const float denom = red[0][lane] + red[1][lane] + red[2][lane] + red[3][lane];
    // v_log_f32 = log2; loss = (log2(denom) - sv2) * ln2
    float lossr = (__builtin_amdgcn_logf(denom) - simTgt[row]) * LN2;
#pragma unroll
    for (int d = 32; d; d >>= 1) lossr += __shfl_xor(lossr, d, 64);
    if (threadIdx.x == 0) {
      // device-scope RMW write: coherent across XCDs, deterministic value
      atomicExch(&blockOut[blockIdx.x], lossr);
      isLast = (atomicAdd(ticket, 1u) == gridDim.x - 1);
    }
  }
  __syncthreads();
  if (isLast && threadIdx.x < 64) {
    // coherent read of all 128 block sums via atomic RMW (+0.0f), fixed order
    float v = atomicAdd(&blockOut[threadIdx.x], 0.0f) +
              atomicAdd(&blockOut[64 + threadIdx.x], 0.0f);
#pragma unroll
    for (int d = 32; d; d >>= 1) v += __shfl_xor(v, d, 64);
    if (threadIdx.x == 0) out[0] = v / (float)N;
  }
}

extern "C" void kernel_launch(void* const* d_in, const int* in_sizes, int n_in,
                              void* d_out, int out_size, void* d_ws, size_t ws_size,
                              hipStream_t stream) {
  const float* ei = (const float*)d_in[0];
  const float* ej = (const float*)d_in[1];
  const int B = in_sizes[0] / D_DIM;  // 4096
  const int N = 2 * B;                // 8192

  char* ws = (char*)d_ws;
  unsigned char* R = (unsigned char*)ws;                                  // N*256 = 2MB (fp8)
  float* rowPartial = (float*)(ws + (size_t)N * D_DIM);                   // 128*N*4 = 4MB
  float* simTgt     = (float*)(ws + (size_t)N * D_DIM + (size_t)128 * N * 4);  // N*4
  float* blockOut   = (float*)((char*)simTgt + (size_t)N * 4);            // 128*4
  unsigned* ticket  = (unsigned*)((char*)blockOut + 128 * 4);             // 4B

  k_normalize<<<N / 16, 256, 0, stream>>>(ei, ej, R, ticket, B);
  const int T = N / 128;
  k_simgemm<<<T * (T + 1) / 2, 256, 0, stream>>>(R, rowPartial, simTgt, N);
  k_rowreduce<<<N / 64, 256, 0, stream>>>(rowPartial, simTgt, blockOut, ticket,
                                          (float*)d_out, N);
}